// Round 10
// baseline (2683.795 us; speedup 1.0000x reference)
//
#include <hip/hip_runtime.h>
#include <stdint.h>
#include <math.h>

#define B_ 64
#define S_ 512
#define I_ 128
#define H_ 2048
#define O_ 128
#define NWG 128            /* r20: 64 WGs per half, 32 cols each */
#define COLS 32
#define NTHREADS 256
#define SLAB (B_ * H_)      /* 131072 elements per h snapshot */
#define HALF_ 65536         /* elements per half-slab */
#define RSTR 36             /* sRed row stride in floats (32 + 4 pad) */
#define SENTW 0x7FC07FC0u   /* qNaN|qNaN — tanh output always has bit14=0 */
#define SENTMASK 0x40004000u

typedef __attribute__((ext_vector_type(8))) __bf16 bf16x8;
typedef __attribute__((ext_vector_type(4))) float floatx4;
typedef __attribute__((ext_vector_type(4))) unsigned int uintx4;
typedef __attribute__((ext_vector_type(2))) unsigned int uintx2;

__device__ __forceinline__ unsigned short f2bf(float f) {
    unsigned u = __float_as_uint(f);
    unsigned r = u + 0x7fffu + ((u >> 16) & 1u);   // RNE
    return (unsigned short)(r >> 16);
}
__device__ __forceinline__ float bf2f(unsigned short h) {
    return __uint_as_float(((unsigned)h) << 16);
}
// tanh(x) = 1 - 2/(e^{2x}+1); err ~1e-6 << bf16 noise.
__device__ __forceinline__ float fast_tanh(float x) {
    float e = __expf(2.0f * x);
    return 1.0f - 2.0f * __builtin_amdgcn_rcpf(e + 1.0f);
}

// VALU work overlapping in-flight VMEM (r16/r18: real cycle reduction).
__device__ __forceinline__ void burn(int n) {
    float a = 1.0f, b = 1.0f;
    const float c = 1.0000001f, d = 0.9999999f;
    for (int i = 0; i < n; ++i)
        asm volatile("v_fmac_f32 %0, %2, %2\n\tv_fmac_f32 %1, %3, %3"
                     : "+v"(a), "+v"(b) : "v"(c), "v"(d));
}

// sc0 sc1 b128 load (bypass L1/L2 -> MALL truth). r19 lesson: NO cached
// h loads — a pre-arrival line cached in L2 serves the stale sentinel
// forever (no invalidation), converting "arrived" into "missing".
#define LDG0(dst, addr) \
    asm volatile("global_load_dwordx4 %0, %1, off sc0 sc1" \
                 : "=v"(dst) : "v"(addr))

// ---- prep kernels -------------------------------------------------------
__global__ void k_wsplit(const float* __restrict__ whh, const float* __restrict__ mask,
                         unsigned short* __restrict__ hi, unsigned short* __restrict__ lo, int n) {
    int i = blockIdx.x * blockDim.x + threadIdx.x;
    int stride = gridDim.x * blockDim.x;
    for (; i < n; i += stride) {
        float w = whh[i] * mask[i];
        unsigned short h = f2bf(w);
        hi[i] = h;
        lo[i] = f2bf(w - bf2f(h));
    }
}
__global__ void k_split(const float* __restrict__ src,
                        unsigned short* __restrict__ hi, unsigned short* __restrict__ lo, int n) {
    int i = blockIdx.x * blockDim.x + threadIdx.x;
    int stride = gridDim.x * blockDim.x;
    for (; i < n; i += stride) {
        float w = src[i];
        unsigned short h = f2bf(w);
        hi[i] = h;
        lo[i] = f2bf(w - bf2f(h));
    }
}
__global__ void k_cast(const float* __restrict__ src, unsigned short* __restrict__ dst, int n) {
    int i = blockIdx.x * blockDim.x + threadIdx.x;
    int stride = gridDim.x * blockDim.x;
    for (; i < n; i += stride) dst[i] = f2bf(src[i]);
}
// fill hs slabs 1..512 with sentinel (sc1 write-through: no dirty copies)
__global__ void k_sent(uintx4* __restrict__ p, int n4) {
    int i = blockIdx.x * blockDim.x + threadIdx.x;
    int stride = gridDim.x * blockDim.x;
    uintx4 s = {SENTW, SENTW, SENTW, SENTW};
    for (; i < n4; i += stride)
        asm volatile("global_store_dwordx4 %0, %1, off sc1"
                     :: "v"(p + i), "v"(s) : "memory");
}

// ---- persistent recurrence kernel --------------------------------------
// Round-20: HALVE THE BROADCAST AMPLIFICATION (COLS 16 -> 32).
//  r18 BW arithmetic: per step every one of 128 consumer WGs per half
//  reads the half's full 128KB h (4 waves span K=2048) => 32 MB/step via
//  sc0sc1 = 7.9 TB/s at 4.03us/step — MALL service ceiling. Protocol
//  variants can't change this; the amplification factor (= WGs per half)
//  can. COLS=32: 64 WGs/half => 16 MB/step, double MFMA per h-byte.
//  Publish block (1024 elems) now maps 1:1 to ONE producer WG: chunk
//  validity = one producer's completion (fan-in 16, was 32).
//  Protocol = r18: all h loads sc0sc1, per-chunk validate, selective
//  retry issued before consuming, burns overlap RT, no flags, no drain.
//  Layout (per half): addr(row,c) = half*65536 + (c>>5)*1024 +
//   (row>>4)*512 + (((c>>3)&3)*16 + (row&15))*8 + (c&7).
__global__ __attribute__((amdgpu_flat_work_group_size(NTHREADS, NTHREADS),
                          amdgpu_waves_per_eu(1, 1))) void k_rnn(
    const unsigned short* __restrict__ whi, const unsigned short* __restrict__ wlo,
    const unsigned short* __restrict__ wihh, const unsigned short* __restrict__ wihl,
    const unsigned short* __restrict__ xbf, const float* __restrict__ bih,
    unsigned short* hs)
{
    __shared__ float sRed[2][4 * 32 * RSTR];
    __shared__ float sBih[COLS];

    const int tid   = threadIdx.x;
    const int wg    = blockIdx.x;
    const int half  = wg >> 6;          // 0: rows 0-31, 1: rows 32-63
    const int wgl   = wg & 63;
    const int j0    = wgl * COLS;
    const int rbase = half * 32;
    const int w     = tid >> 6;
    const int lane  = tid & 63;
    const int q     = lane >> 4;
    const int nn    = lane & 15;
    const int kb    = w * 512;   // this wave's k range in H
    const int xkb   = w * 32;    // this wave's k range in I

    if (tid < COLS) sBih[tid] = bih[j0 + tid];

    // W fragments — loaded once, laundered opaque (stay resident).
    // Two 16-col B-tiles (A: j0.., B: j0+16..), hi+lo: 256 VGPRs.
    uintx4 whA[16], wlA[16], whB[16], wlB[16];
    uintx4 bxhA_u, bxlA_u, bxhB_u, bxlB_u;
    {
        const size_t wrowA = (size_t)(j0 + nn)      * H_ + (size_t)(kb + q * 8);
        const size_t wrowB = (size_t)(j0 + 16 + nn) * H_ + (size_t)(kb + q * 8);
#pragma unroll
        for (int ks = 0; ks < 16; ++ks) {
            whA[ks] = *(const uintx4*)&whi[wrowA + ks * 32];
            wlA[ks] = *(const uintx4*)&wlo[wrowA + ks * 32];
            whB[ks] = *(const uintx4*)&whi[wrowB + ks * 32];
            wlB[ks] = *(const uintx4*)&wlo[wrowB + ks * 32];
        }
        const size_t xrowA = (size_t)(j0 + nn)      * I_ + (size_t)(xkb + q * 8);
        const size_t xrowB = (size_t)(j0 + 16 + nn) * I_ + (size_t)(xkb + q * 8);
        bxhA_u = *(const uintx4*)&wihh[xrowA];
        bxlA_u = *(const uintx4*)&wihl[xrowA];
        bxhB_u = *(const uintx4*)&wihh[xrowB];
        bxlB_u = *(const uintx4*)&wihl[xrowB];
#pragma unroll
        for (int ks = 0; ks < 16; ++ks)
            asm volatile("" : "+v"(whA[ks]), "+v"(wlA[ks]),
                              "+v"(whB[ks]), "+v"(wlB[ks]));
        asm volatile("" : "+v"(bxhA_u), "+v"(bxlA_u),
                          "+v"(bxhB_u), "+v"(bxlB_u));
    }
    const bf16x8 bxhA = __builtin_bit_cast(bf16x8, bxhA_u);
    const bf16x8 bxlA = __builtin_bit_cast(bf16x8, bxlA_u);
    const bf16x8 bxhB = __builtin_bit_cast(bf16x8, bxhB_u);
    const bf16x8 bxlB = __builtin_bit_cast(bf16x8, bxlB_u);

    // consumer base: wave w's 16 blocks start at half*65536 + w*16384;
    // per-lane segment = lane*16B. (+t*SLAB per step)
    const unsigned short* const cwbase =
        hs + (size_t)half * HALF_ + (size_t)w * 16384 + (size_t)lane * 8;

    // producer publish offset: 256 threads, row m=tid>>3, cols n0..n0+3;
    // whole WG fills exactly block wgl (2KB dense).
    const int m  = tid >> 3;
    const int n0 = (tid & 7) * 4;
    const size_t pub_off =
        (size_t)half * HALF_ + (size_t)wgl * 1024 +
        (size_t)(m >> 4) * 512 +
        (size_t)(((n0 >> 3) & 3) * 16 + (m & 15)) * 8 +
        (size_t)(n0 & 7);

    // x rows for this WG's two row-tiles
    const unsigned short* const xr0 = xbf + (size_t)(rbase + nn)      * (S_ * I_);
    const unsigned short* const xr1 = xbf + (size_t)(rbase + 16 + nn) * (S_ * I_);

    // prologue: prefetch x operands for t=0
    uintx4 xc0, xc1;
    {
        const size_t xo = (size_t)xkb + q * 8;
        xc0 = *(const uintx4*)&xr0[xo];
        xc1 = *(const uintx4*)&xr1[xo];
        asm volatile("" : "+v"(xc0), "+v"(xc1));
    }

#pragma unroll 1
    for (int t = 0; t < S_; ++t) {
        const unsigned short* cb = cwbase + (size_t)t * SLAB;

        // (1) issue ALL 32 h-loads immediately (they are also the probe)
        uintx4 g0[16], g1[16];
#pragma unroll
        for (int ks = 0; ks < 16; ++ks) {
            LDG0(g0[ks], cb + ks * 1024);        // rows 0-15 of half
            LDG0(g1[ks], cb + ks * 1024 + 512);  // rows 16-31 of half
        }

        // (2) register-only x-projection — overlaps the load RT
        floatx4 a00 = {0.f, 0.f, 0.f, 0.f}, a01 = a00, a10 = a00, a11 = a00;
        {
            bf16x8 x0 = __builtin_bit_cast(bf16x8, xc0);
            bf16x8 x1 = __builtin_bit_cast(bf16x8, xc1);
            a00 = __builtin_amdgcn_mfma_f32_16x16x32_bf16(x0, bxhA, a00, 0, 0, 0);
            a01 = __builtin_amdgcn_mfma_f32_16x16x32_bf16(x0, bxhB, a01, 0, 0, 0);
            a10 = __builtin_amdgcn_mfma_f32_16x16x32_bf16(x1, bxhA, a10, 0, 0, 0);
            a11 = __builtin_amdgcn_mfma_f32_16x16x32_bf16(x1, bxhB, a11, 0, 0, 0);
            a00 = __builtin_amdgcn_mfma_f32_16x16x32_bf16(x0, bxlA, a00, 0, 0, 0);
            a01 = __builtin_amdgcn_mfma_f32_16x16x32_bf16(x0, bxlB, a01, 0, 0, 0);
            a10 = __builtin_amdgcn_mfma_f32_16x16x32_bf16(x1, bxlA, a10, 0, 0, 0);
            a11 = __builtin_amdgcn_mfma_f32_16x16x32_bf16(x1, bxlB, a11, 0, 0, 0);
        }

        // (3) issue next-step x loads (land at loop end)
        uintx4 xn0, xn1;
        {
            const size_t xo = (size_t)((t + 1) & (S_ - 1)) * I_ + xkb + q * 8;
            xn0 = *(const uintx4*)&xr0[xo];
            xn1 = *(const uintx4*)&xr1[xo];
        }

        // anti-stall: overlap the in-flight RT with VALU work
        burn(96);

        // (4) validate per chunk; MFMA valid chunks; selective retry.
        asm volatile("s_waitcnt vmcnt(0)" ::: "memory");
        __builtin_amdgcn_sched_barrier(0);
        unsigned rem = 0xFFFFu;
        for (;;) {
            unsigned nv = 0;
#pragma unroll
            for (int ks = 0; ks < 16; ++ks) if (rem & (1u << ks)) {
                unsigned o = g0[ks].x | g0[ks].y | g0[ks].z | g0[ks].w
                           | g1[ks].x | g1[ks].y | g1[ks].z | g1[ks].w;
                if (__ballot((o & SENTMASK) != 0u) == 0ull) nv |= 1u << ks;
            }
            nv = __builtin_amdgcn_readfirstlane(nv);
            const unsigned rem2 = rem & ~nv;
            // re-issue stragglers FIRST (their RT overlaps the MFMAs)
            if (rem2) {
#pragma unroll
                for (int ks = 0; ks < 16; ++ks) if (rem2 & (1u << ks)) {
                    LDG0(g0[ks], cb + ks * 1024);
                    LDG0(g1[ks], cb + ks * 1024 + 512);
                }
            }
            // consume newly-valid chunks (accumulation order irrelevant)
#pragma unroll
            for (int ks = 0; ks < 16; ++ks) if (nv & (1u << ks)) {
                const bf16x8 h0 = __builtin_bit_cast(bf16x8, g0[ks]);
                const bf16x8 h1 = __builtin_bit_cast(bf16x8, g1[ks]);
                const bf16x8 hA = __builtin_bit_cast(bf16x8, whA[ks]);
                const bf16x8 lA = __builtin_bit_cast(bf16x8, wlA[ks]);
                const bf16x8 hB = __builtin_bit_cast(bf16x8, whB[ks]);
                const bf16x8 lB = __builtin_bit_cast(bf16x8, wlB[ks]);
                a00 = __builtin_amdgcn_mfma_f32_16x16x32_bf16(h0, hA, a00, 0, 0, 0);
                a01 = __builtin_amdgcn_mfma_f32_16x16x32_bf16(h0, hB, a01, 0, 0, 0);
                a10 = __builtin_amdgcn_mfma_f32_16x16x32_bf16(h1, hA, a10, 0, 0, 0);
                a11 = __builtin_amdgcn_mfma_f32_16x16x32_bf16(h1, hB, a11, 0, 0, 0);
                a00 = __builtin_amdgcn_mfma_f32_16x16x32_bf16(h0, lA, a00, 0, 0, 0);
                a01 = __builtin_amdgcn_mfma_f32_16x16x32_bf16(h0, lB, a01, 0, 0, 0);
                a10 = __builtin_amdgcn_mfma_f32_16x16x32_bf16(h1, lA, a10, 0, 0, 0);
                a11 = __builtin_amdgcn_mfma_f32_16x16x32_bf16(h1, lB, a11, 0, 0, 0);
            }
            if (!rem2) break;
            if (nv == 0) burn(96);   // stall path: stay busy, overlap RT
            rem = rem2;
            asm volatile("s_waitcnt vmcnt(0)" ::: "memory");
            __builtin_amdgcn_sched_barrier(0);
        }

        // (5) wave partials -> LDS (buffer t&1); 32 rows x 32 cols
        float* sr = sRed[t & 1];
#pragma unroll
        for (int r = 0; r < 4; ++r) {
            sr[(w * 32 +      q * 4 + r) * RSTR + nn]      = a00[r];
            sr[(w * 32 +      q * 4 + r) * RSTR + 16 + nn] = a01[r];
            sr[(w * 32 + 16 + q * 4 + r) * RSTR + nn]      = a10[r];
            sr[(w * 32 + 16 + q * 4 + r) * RSTR + 16 + nn] = a11[r];
        }
        __syncthreads();   // sRed ready (also isolates t vs t+2 buffer reuse)

        // (6) reduce 4 waves, +bih, tanh, pack, sc1 dwordx2 store into
        //     publish layout. All 256 threads: row m, 4 cols each.
        {
            floatx4 s = *(const floatx4*)&sr[(0 * 32 + m) * RSTR + n0];
            s += *(const floatx4*)&sr[(1 * 32 + m) * RSTR + n0];
            s += *(const floatx4*)&sr[(2 * 32 + m) * RSTR + n0];
            s += *(const floatx4*)&sr[(3 * 32 + m) * RSTR + n0];
            unsigned short u0 = f2bf(fast_tanh(s[0] + sBih[n0 + 0]));
            unsigned short u1 = f2bf(fast_tanh(s[1] + sBih[n0 + 1]));
            unsigned short u2 = f2bf(fast_tanh(s[2] + sBih[n0 + 2]));
            unsigned short u3 = f2bf(fast_tanh(s[3] + sBih[n0 + 3]));
            uintx2 pk;
            pk.x = (unsigned)u0 | ((unsigned)u1 << 16);
            pk.y = (unsigned)u2 | ((unsigned)u3 << 16);
            unsigned short* dst = hs + (size_t)(t + 1) * SLAB + pub_off;
            asm volatile("global_store_dwordx2 %0, %1, off sc1"
                         :: "v"(dst), "v"(pk) : "memory");
        }

        asm volatile("" : "+v"(xn0), "+v"(xn1));   // land x prefetch here
        xc0 = xn0; xc1 = xn1;
    }
}

// ---- output projection: out[b,t,o] = hs[t+1][b,:] . Who[o,:] + bho ------
// hflat points at slab 1; slabs are in PUBLISH layout (see k_rnn header).
__global__ __launch_bounds__(NTHREADS) void k_out(
    const unsigned short* __restrict__ hflat, const unsigned short* __restrict__ who,
    const float* __restrict__ bho, float* __restrict__ out)
{
    const int tid = threadIdx.x;
    const int w = tid >> 6, lane = tid & 63, q = lane >> 4, nn = lane & 15;
    const int r0 = ((int)blockIdx.x * 4 + w) * 16;   // flat row = t*64+b
    const int t    = r0 >> 6;
    const int half = (r0 >> 5) & 1;
    const int rb   = (r0 >> 4) & 1;
    // A base in publish layout: lane-ordered 16B segments, +ks*1024/iter
    const unsigned short* const abase =
        hflat + (size_t)t * SLAB + (size_t)half * HALF_ +
        (size_t)rb * 512 + (size_t)lane * 8;
    floatx4 acc[8];
#pragma unroll
    for (int i = 0; i < 8; ++i) acc[i] = floatx4{0.f, 0.f, 0.f, 0.f};
    for (int ks = 0; ks < 64; ++ks) {
        const int kk = ks * 32 + q * 8;
        bf16x8 a = *(const bf16x8*)(abase + ks * 1024);
#pragma unroll
        for (int nt = 0; nt < 8; ++nt) {
            bf16x8 b = *(const bf16x8*)&who[(size_t)(nt * 16 + nn) * H_ + kk];
            acc[nt] = __builtin_amdgcn_mfma_f32_16x16x32_bf16(a, b, acc[nt], 0, 0, 0);
        }
    }
#pragma unroll
    for (int nt = 0; nt < 8; ++nt) {
#pragma unroll
        for (int r = 0; r < 4; ++r) {
            int rr = r0 + q * 4 + r;
            int tt = rr >> 6, b = rr & 63;
            int o = nt * 16 + nn;
            out[(size_t)b * (S_ * O_) + (size_t)tt * O_ + o] = acc[nt][r] + bho[o];
        }
    }
}

// ---- host ----------------------------------------------------------------
extern "C" void kernel_launch(void* const* d_in, const int* in_sizes, int n_in,
                              void* d_out, int out_size, void* d_ws, size_t ws_size,
                              hipStream_t stream) {
    const float* x    = (const float*)d_in[0];
    const float* Wih  = (const float*)d_in[1];
    const float* bih  = (const float*)d_in[2];
    const float* Whh  = (const float*)d_in[3];
    const float* Who  = (const float*)d_in[4];
    const float* bho  = (const float*)d_in[5];
    const float* mask = (const float*)d_in[6];
    float* out = (float*)d_out;

    char* ws = (char*)d_ws;
    constexpr size_t HS_OFF   = 0;
    constexpr size_t HS_BYTES = (size_t)(S_ + 1) * SLAB * 2;
    constexpr size_t WHI_OFF  = HS_OFF + HS_BYTES;
    constexpr size_t WLO_OFF  = WHI_OFF + (size_t)H_ * H_ * 2;
    constexpr size_t XBF_OFF  = WLO_OFF + (size_t)H_ * H_ * 2;
    constexpr size_t WIHH_OFF = XBF_OFF + (size_t)B_ * S_ * I_ * 2;
    constexpr size_t WIHL_OFF = WIHH_OFF + (size_t)H_ * I_ * 2;
    constexpr size_t WHO_OFF  = WIHL_OFF + (size_t)H_ * I_ * 2;
    constexpr size_t WS_NEED  = WHO_OFF + (size_t)O_ * H_ * 2;
    if (ws_size < WS_NEED) return;

    unsigned short* hs    = (unsigned short*)(ws + HS_OFF);
    unsigned short* whi   = (unsigned short*)(ws + WHI_OFF);
    unsigned short* wlo   = (unsigned short*)(ws + WLO_OFF);
    unsigned short* xbf   = (unsigned short*)(ws + XBF_OFF);
    unsigned short* wihh  = (unsigned short*)(ws + WIHH_OFF);
    unsigned short* wihl  = (unsigned short*)(ws + WIHL_OFF);
    unsigned short* whobf = (unsigned short*)(ws + WHO_OFF);

    hipMemsetAsync(hs, 0, (size_t)SLAB * 2, stream);      // h(0) = 0 (any layout)
    // slabs 1..512 := sentinel (bit14 set) — data-arrival detector
    k_sent<<<2048, 256, 0, stream>>>((uintx4*)(hs + SLAB),
                                     (int)((size_t)S_ * SLAB / 8));

    k_wsplit<<<1024, 256, 0, stream>>>(Whh, mask, whi, wlo, H_ * H_);
    k_split <<<256, 256, 0, stream>>>(Wih, wihh, wihl, H_ * I_);
    k_cast  <<<256, 256, 0, stream>>>(Who, whobf, O_ * H_);
    k_cast  <<<1024, 256, 0, stream>>>(x, xbf, B_ * S_ * I_);

    k_rnn<<<NWG, NTHREADS, 0, stream>>>(whi, wlo, wihh, wihl, xbf, bih, hs);
    k_out<<<512, NTHREADS, 0, stream>>>(hs + SLAB, whobf, bho, out);
}

// Round 11
// 2424.048 us; speedup vs baseline: 1.1072x; 1.1072x over previous
//
#include <hip/hip_runtime.h>
#include <stdint.h>
#include <math.h>

#define B_ 64
#define S_ 512
#define I_ 128
#define H_ 2048
#define O_ 128
#define NWG 256            /* r21: 4 quarters x 64 WGs; 16 rows x 32 cols each */
#define COLS 32
#define NTHREADS 256
#define SLAB (B_ * H_)      /* 131072 elements per h snapshot */
#define QTR_ 32768          /* elements per quarter-slab (16 rows x 2048) */
#define RSTR 36             /* sRed row stride in floats (32 + 4 pad) */
#define SENTW 0x7FC07FC0u   /* qNaN|qNaN — tanh output always has bit14=0 */
#define SENTMASK 0x40004000u

typedef __attribute__((ext_vector_type(8))) __bf16 bf16x8;
typedef __attribute__((ext_vector_type(4))) float floatx4;
typedef __attribute__((ext_vector_type(2))) float floatx2;
typedef __attribute__((ext_vector_type(4))) unsigned int uintx4;

__device__ __forceinline__ unsigned short f2bf(float f) {
    unsigned u = __float_as_uint(f);
    unsigned r = u + 0x7fffu + ((u >> 16) & 1u);   // RNE
    return (unsigned short)(r >> 16);
}
__device__ __forceinline__ float bf2f(unsigned short h) {
    return __uint_as_float(((unsigned)h) << 16);
}
// tanh(x) = 1 - 2/(e^{2x}+1); err ~1e-6 << bf16 noise.
__device__ __forceinline__ float fast_tanh(float x) {
    float e = __expf(2.0f * x);
    return 1.0f - 2.0f * __builtin_amdgcn_rcpf(e + 1.0f);
}

// VALU work overlapping in-flight VMEM (r16/r18: real cycle reduction).
__device__ __forceinline__ void burn(int n) {
    float a = 1.0f, b = 1.0f;
    const float c = 1.0000001f, d = 0.9999999f;
    for (int i = 0; i < n; ++i)
        asm volatile("v_fmac_f32 %0, %2, %2\n\tv_fmac_f32 %1, %3, %3"
                     : "+v"(a), "+v"(b) : "v"(c), "v"(d));
}

// sc0 sc1 b128 load (bypass L1/L2 -> MALL truth). r19 lesson: NO cached
// h loads — a pre-arrival line cached in L2 serves the stale sentinel
// forever (no invalidation).
#define LDG0(dst, addr) \
    asm volatile("global_load_dwordx4 %0, %1, off sc0 sc1" \
                 : "=v"(dst) : "v"(addr))

// ---- prep kernels -------------------------------------------------------
__global__ void k_wsplit(const float* __restrict__ whh, const float* __restrict__ mask,
                         unsigned short* __restrict__ hi, unsigned short* __restrict__ lo, int n) {
    int i = blockIdx.x * blockDim.x + threadIdx.x;
    int stride = gridDim.x * blockDim.x;
    for (; i < n; i += stride) {
        float w = whh[i] * mask[i];
        unsigned short h = f2bf(w);
        hi[i] = h;
        lo[i] = f2bf(w - bf2f(h));
    }
}
__global__ void k_split(const float* __restrict__ src,
                        unsigned short* __restrict__ hi, unsigned short* __restrict__ lo, int n) {
    int i = blockIdx.x * blockDim.x + threadIdx.x;
    int stride = gridDim.x * blockDim.x;
    for (; i < n; i += stride) {
        float w = src[i];
        unsigned short h = f2bf(w);
        hi[i] = h;
        lo[i] = f2bf(w - bf2f(h));
    }
}
__global__ void k_cast(const float* __restrict__ src, unsigned short* __restrict__ dst, int n) {
    int i = blockIdx.x * blockDim.x + threadIdx.x;
    int stride = gridDim.x * blockDim.x;
    for (; i < n; i += stride) dst[i] = f2bf(src[i]);
}
// fill hs slabs 1..512 with sentinel (sc1 write-through: no dirty copies)
__global__ void k_sent(uintx4* __restrict__ p, int n4) {
    int i = blockIdx.x * blockDim.x + threadIdx.x;
    int stride = gridDim.x * blockDim.x;
    uintx4 s = {SENTW, SENTW, SENTW, SENTW};
    for (; i < n4; i += stride)
        asm volatile("global_store_dwordx4 %0, %1, off sc1"
                     :: "v"(p + i), "v"(s) : "memory");
}

// ---- persistent recurrence kernel --------------------------------------
// Round-21: QUARTER-SPLIT — COLS=32 traffic reduction AT FULL CHIP.
//  r20 (COLS=32, 128 WGs) showed traffic halving alone doesn't pay when
//  half the CUs idle: step = L_fixed(~3.2us?) + per-CU work. This round
//  keeps COLS=32 (broadcast = 512MB/COLS = 16 MB/step) with 256 WGs by
//  splitting the independent batch rows into 4 quarters of 16:
//    WG(qt=wg>>6, wgl=wg&63): rows qt*16..+15, cols wgl*32..+31.
//  Per wave: 16 b128 loads/step (chunk == ONE producer's 1KB block,
//  fan-in 1), 68 MFMAs, W resident 256 VGPRs (AGPR-parked by compiler).
//  Discriminator: traffic halved at constant CUs/MFMA. BW-bound -> ~2x;
//  fixed-latency-bound -> flat, next round attacks the serial chain.
//  Slab layout (per quarter, 64 blocks of 512 elems):
//   elem(row r in 0..15, col c) -> qt*32768 + (c>>5)*512
//                                  + (((c>>3)&3)*16 + r)*8 + (c&7)
__global__ __attribute__((amdgpu_flat_work_group_size(NTHREADS, NTHREADS),
                          amdgpu_waves_per_eu(1, 1))) void k_rnn(
    const unsigned short* __restrict__ whi, const unsigned short* __restrict__ wlo,
    const unsigned short* __restrict__ wihh, const unsigned short* __restrict__ wihl,
    const unsigned short* __restrict__ xbf, const float* __restrict__ bih,
    unsigned short* hs)
{
    __shared__ float sRed[2][4 * 16 * RSTR];
    __shared__ float sBih[COLS];

    const int tid   = threadIdx.x;
    const int wg    = blockIdx.x;
    const int qt    = wg >> 6;          // quarter: rows qt*16..qt*16+15
    const int wgl   = wg & 63;
    const int j0    = wgl * COLS;
    const int rbase = qt * 16;
    const int w     = tid >> 6;
    const int lane  = tid & 63;
    const int q     = lane >> 4;
    const int nn    = lane & 15;
    const int kb    = w * 512;   // this wave's k range in H
    const int xkb   = w * 32;    // this wave's k range in I

    if (tid < COLS) sBih[tid] = bih[j0 + tid];

    // W fragments — loaded once, laundered opaque (stay resident).
    // Two 16-col tiles (A: j0.., B: j0+16..), hi+lo: 256 VGPRs.
    uintx4 whA[16], wlA[16], whB[16], wlB[16];
    uintx4 bxhA_u, bxlA_u, bxhB_u, bxlB_u;
    {
        const size_t wrowA = (size_t)(j0 + nn)      * H_ + (size_t)(kb + q * 8);
        const size_t wrowB = (size_t)(j0 + 16 + nn) * H_ + (size_t)(kb + q * 8);
#pragma unroll
        for (int ks = 0; ks < 16; ++ks) {
            whA[ks] = *(const uintx4*)&whi[wrowA + ks * 32];
            wlA[ks] = *(const uintx4*)&wlo[wrowA + ks * 32];
            whB[ks] = *(const uintx4*)&whi[wrowB + ks * 32];
            wlB[ks] = *(const uintx4*)&wlo[wrowB + ks * 32];
        }
        const size_t xrowA = (size_t)(j0 + nn)      * I_ + (size_t)(xkb + q * 8);
        const size_t xrowB = (size_t)(j0 + 16 + nn) * I_ + (size_t)(xkb + q * 8);
        bxhA_u = *(const uintx4*)&wihh[xrowA];
        bxlA_u = *(const uintx4*)&wihl[xrowA];
        bxhB_u = *(const uintx4*)&wihh[xrowB];
        bxlB_u = *(const uintx4*)&wihl[xrowB];
#pragma unroll
        for (int ks = 0; ks < 16; ++ks)
            asm volatile("" : "+v"(whA[ks]), "+v"(wlA[ks]),
                              "+v"(whB[ks]), "+v"(wlB[ks]));
        asm volatile("" : "+v"(bxhA_u), "+v"(bxlA_u),
                          "+v"(bxhB_u), "+v"(bxlB_u));
    }
    const bf16x8 bxhA = __builtin_bit_cast(bf16x8, bxhA_u);
    const bf16x8 bxlA = __builtin_bit_cast(bf16x8, bxlA_u);
    const bf16x8 bxhB = __builtin_bit_cast(bf16x8, bxhB_u);
    const bf16x8 bxlB = __builtin_bit_cast(bf16x8, bxlB_u);

    // consumer base: wave w reads blocks w*16+ks of quarter qt;
    // per-lane segment = lane*16B. (+t*SLAB per step)
    const unsigned short* const cwbase =
        hs + (size_t)qt * QTR_ + (size_t)w * 8192 + (size_t)lane * 8;

    // producer publish offset: block wgl of quarter qt; 256 threads,
    // row m=tid>>4 (0..15), col pair n0=(tid&15)*2.
    const int m  = tid >> 4;
    const int n0 = (tid & 15) * 2;
    const size_t pub_off =
        (size_t)qt * QTR_ + (size_t)wgl * 512 +
        (size_t)(((n0 >> 3) & 3) * 16 + m) * 8 + (size_t)(n0 & 7);

    // x row for this WG's single 16-row tile
    const unsigned short* const xr0 = xbf + (size_t)(rbase + nn) * (S_ * I_);

    // prologue: prefetch x operand for t=0
    uintx4 xc0;
    {
        xc0 = *(const uintx4*)&xr0[(size_t)xkb + q * 8];
        asm volatile("" : "+v"(xc0));
    }

#pragma unroll 1
    for (int t = 0; t < S_; ++t) {
        const unsigned short* cb = cwbase + (size_t)t * SLAB;

        // (1) issue ALL 16 h-loads immediately (they are also the probe)
        uintx4 g[16];
#pragma unroll
        for (int ks = 0; ks < 16; ++ks)
            LDG0(g[ks], cb + ks * 512);

        // (2) register-only x-projection — overlaps the load RT
        floatx4 a00 = {0.f, 0.f, 0.f, 0.f}, a01 = a00;
        {
            bf16x8 x0 = __builtin_bit_cast(bf16x8, xc0);
            a00 = __builtin_amdgcn_mfma_f32_16x16x32_bf16(x0, bxhA, a00, 0, 0, 0);
            a01 = __builtin_amdgcn_mfma_f32_16x16x32_bf16(x0, bxhB, a01, 0, 0, 0);
            a00 = __builtin_amdgcn_mfma_f32_16x16x32_bf16(x0, bxlA, a00, 0, 0, 0);
            a01 = __builtin_amdgcn_mfma_f32_16x16x32_bf16(x0, bxlB, a01, 0, 0, 0);
        }

        // (3) issue next-step x load (lands at loop end)
        uintx4 xn0;
        xn0 = *(const uintx4*)&xr0[(size_t)((t + 1) & (S_ - 1)) * I_ + xkb + q * 8];

        // anti-stall: overlap the in-flight RT with VALU work
        burn(96);

        // (4) validate per chunk; MFMA valid chunks; selective retry.
        asm volatile("s_waitcnt vmcnt(0)" ::: "memory");
        __builtin_amdgcn_sched_barrier(0);
        unsigned rem = 0xFFFFu;
        for (;;) {
            unsigned nv = 0;
#pragma unroll
            for (int ks = 0; ks < 16; ++ks) if (rem & (1u << ks)) {
                unsigned o = g[ks].x | g[ks].y | g[ks].z | g[ks].w;
                if (__ballot((o & SENTMASK) != 0u) == 0ull) nv |= 1u << ks;
            }
            nv = __builtin_amdgcn_readfirstlane(nv);
            const unsigned rem2 = rem & ~nv;
            // re-issue stragglers FIRST (their RT overlaps the MFMAs)
            if (rem2) {
#pragma unroll
                for (int ks = 0; ks < 16; ++ks) if (rem2 & (1u << ks))
                    LDG0(g[ks], cb + ks * 512);
            }
            // consume newly-valid chunks (accumulation order irrelevant)
#pragma unroll
            for (int ks = 0; ks < 16; ++ks) if (nv & (1u << ks)) {
                const bf16x8 h0 = __builtin_bit_cast(bf16x8, g[ks]);
                const bf16x8 hA = __builtin_bit_cast(bf16x8, whA[ks]);
                const bf16x8 lA = __builtin_bit_cast(bf16x8, wlA[ks]);
                const bf16x8 hB = __builtin_bit_cast(bf16x8, whB[ks]);
                const bf16x8 lB = __builtin_bit_cast(bf16x8, wlB[ks]);
                a00 = __builtin_amdgcn_mfma_f32_16x16x32_bf16(h0, hA, a00, 0, 0, 0);
                a01 = __builtin_amdgcn_mfma_f32_16x16x32_bf16(h0, hB, a01, 0, 0, 0);
                a00 = __builtin_amdgcn_mfma_f32_16x16x32_bf16(h0, lA, a00, 0, 0, 0);
                a01 = __builtin_amdgcn_mfma_f32_16x16x32_bf16(h0, lB, a01, 0, 0, 0);
            }
            if (!rem2) break;
            if (nv == 0) burn(96);   // stall path: stay busy, overlap RT
            rem = rem2;
            asm volatile("s_waitcnt vmcnt(0)" ::: "memory");
            __builtin_amdgcn_sched_barrier(0);
        }

        // (5) wave partials -> LDS (buffer t&1); 16 rows x 32 cols
        float* sr = sRed[t & 1];
#pragma unroll
        for (int r = 0; r < 4; ++r) {
            sr[(w * 16 + q * 4 + r) * RSTR + nn]      = a00[r];
            sr[(w * 16 + q * 4 + r) * RSTR + 16 + nn] = a01[r];
        }
        __syncthreads();   // sRed ready (also isolates t vs t+2 buffer reuse)

        // (6) reduce 4 waves, +bih, tanh, pack, sc1 dword store into
        //     publish layout. 256 threads: row m, col pair n0.
        {
            floatx2 s = *(const floatx2*)&sr[(0 * 16 + m) * RSTR + n0];
            s += *(const floatx2*)&sr[(1 * 16 + m) * RSTR + n0];
            s += *(const floatx2*)&sr[(2 * 16 + m) * RSTR + n0];
            s += *(const floatx2*)&sr[(3 * 16 + m) * RSTR + n0];
            unsigned short u0 = f2bf(fast_tanh(s[0] + sBih[n0 + 0]));
            unsigned short u1 = f2bf(fast_tanh(s[1] + sBih[n0 + 1]));
            unsigned pk = (unsigned)u0 | ((unsigned)u1 << 16);
            unsigned short* dst = hs + (size_t)(t + 1) * SLAB + pub_off;
            asm volatile("global_store_dword %0, %1, off sc1"
                         :: "v"(dst), "v"(pk) : "memory");
        }

        asm volatile("" : "+v"(xn0));   // land x prefetch here
        xc0 = xn0;
    }
}

// ---- output projection: out[b,t,o] = hs[t+1][b,:] . Who[o,:] + bho ------
// hflat points at slab 1; slabs are in PUBLISH layout (see k_rnn header).
__global__ __launch_bounds__(NTHREADS) void k_out(
    const unsigned short* __restrict__ hflat, const unsigned short* __restrict__ who,
    const float* __restrict__ bho, float* __restrict__ out)
{
    const int tid = threadIdx.x;
    const int w = tid >> 6, lane = tid & 63, q = lane >> 4, nn = lane & 15;
    const int r0 = ((int)blockIdx.x * 4 + w) * 16;   // flat row = t*64+b
    const int t  = r0 >> 6;
    const int qt = (r0 >> 4) & 3;
    // A base in publish layout: lane-ordered 16B segments, +ks*512/iter
    const unsigned short* const abase =
        hflat + (size_t)t * SLAB + (size_t)qt * QTR_ + (size_t)lane * 8;
    floatx4 acc[8];
#pragma unroll
    for (int i = 0; i < 8; ++i) acc[i] = floatx4{0.f, 0.f, 0.f, 0.f};
    for (int ks = 0; ks < 64; ++ks) {
        const int kk = ks * 32 + q * 8;
        bf16x8 a = *(const bf16x8*)(abase + ks * 512);
#pragma unroll
        for (int nt = 0; nt < 8; ++nt) {
            bf16x8 b = *(const bf16x8*)&who[(size_t)(nt * 16 + nn) * H_ + kk];
            acc[nt] = __builtin_amdgcn_mfma_f32_16x16x32_bf16(a, b, acc[nt], 0, 0, 0);
        }
    }
#pragma unroll
    for (int nt = 0; nt < 8; ++nt) {
#pragma unroll
        for (int r = 0; r < 4; ++r) {
            int rr = r0 + q * 4 + r;
            int tt = rr >> 6, b = rr & 63;
            int o = nt * 16 + nn;
            out[(size_t)b * (S_ * O_) + (size_t)tt * O_ + o] = acc[nt][r] + bho[o];
        }
    }
}

// ---- host ----------------------------------------------------------------
extern "C" void kernel_launch(void* const* d_in, const int* in_sizes, int n_in,
                              void* d_out, int out_size, void* d_ws, size_t ws_size,
                              hipStream_t stream) {
    const float* x    = (const float*)d_in[0];
    const float* Wih  = (const float*)d_in[1];
    const float* bih  = (const float*)d_in[2];
    const float* Whh  = (const float*)d_in[3];
    const float* Who  = (const float*)d_in[4];
    const float* bho  = (const float*)d_in[5];
    const float* mask = (const float*)d_in[6];
    float* out = (float*)d_out;

    char* ws = (char*)d_ws;
    constexpr size_t HS_OFF   = 0;
    constexpr size_t HS_BYTES = (size_t)(S_ + 1) * SLAB * 2;
    constexpr size_t WHI_OFF  = HS_OFF + HS_BYTES;
    constexpr size_t WLO_OFF  = WHI_OFF + (size_t)H_ * H_ * 2;
    constexpr size_t XBF_OFF  = WLO_OFF + (size_t)H_ * H_ * 2;
    constexpr size_t WIHH_OFF = XBF_OFF + (size_t)B_ * S_ * I_ * 2;
    constexpr size_t WIHL_OFF = WIHH_OFF + (size_t)H_ * I_ * 2;
    constexpr size_t WHO_OFF  = WIHL_OFF + (size_t)H_ * I_ * 2;
    constexpr size_t WS_NEED  = WHO_OFF + (size_t)O_ * H_ * 2;
    if (ws_size < WS_NEED) return;

    unsigned short* hs    = (unsigned short*)(ws + HS_OFF);
    unsigned short* whi   = (unsigned short*)(ws + WHI_OFF);
    unsigned short* wlo   = (unsigned short*)(ws + WLO_OFF);
    unsigned short* xbf   = (unsigned short*)(ws + XBF_OFF);
    unsigned short* wihh  = (unsigned short*)(ws + WIHH_OFF);
    unsigned short* wihl  = (unsigned short*)(ws + WIHL_OFF);
    unsigned short* whobf = (unsigned short*)(ws + WHO_OFF);

    hipMemsetAsync(hs, 0, (size_t)SLAB * 2, stream);      // h(0) = 0 (any layout)
    // slabs 1..512 := sentinel (bit14 set) — data-arrival detector
    k_sent<<<2048, 256, 0, stream>>>((uintx4*)(hs + SLAB),
                                     (int)((size_t)S_ * SLAB / 8));

    k_wsplit<<<1024, 256, 0, stream>>>(Whh, mask, whi, wlo, H_ * H_);
    k_split <<<256, 256, 0, stream>>>(Wih, wihh, wihl, H_ * I_);
    k_cast  <<<256, 256, 0, stream>>>(Who, whobf, O_ * H_);
    k_cast  <<<1024, 256, 0, stream>>>(x, xbf, B_ * S_ * I_);

    k_rnn<<<NWG, NTHREADS, 0, stream>>>(whi, wlo, wihh, wihl, xbf, bih, hs);
    k_out<<<512, NTHREADS, 0, stream>>>(hs + SLAB, whobf, bho, out);
}